// Round 1
// baseline (145.414 us; speedup 1.0000x reference)
//
#include <hip/hip_runtime.h>

// SE3 loss, round 6: LDS-staged coalesced streaming.
// Previous round was latency-bound: 1024 blocks (4 wg/CU), 19 float4 loads per
// thread at 144B wave-stride (each wave-load scattered across ~64 granules),
// one-shot load->compute with no pipelining. HBM 20%, VALU 15%, occ 22%.
// New structure: 4096 blocks, each stages a 256-element tile into LDS with
// fully coalesced float4 loads (64x16B contiguous per wave-load), then
// 1 element/thread computes out of LDS (stride-9/7/3 reads = <=2-way bank
// aliasing, free). 19.5KB LDS -> 8 blocks/CU resident -> 32 waves/CU; block
// turnover pipelines staging of new blocks under compute of resident ones.
//
// Math per element unchanged (verified, absmax 0.0):
//  - G (gt rotation): closed-form SVD polar factor of the unnormalized-quat
//    matrix: polar(G) = (c/r)I + ((1-c/r)/v^2) vv^T + (2w/r)[v]x.
//  - P (pred_R): 3 determinant-scaled Newton iterations + 1 unscaled polish;
//    sign(det0) flip folded into final iteration's coefficients.
//  - rot loss: ||P^T G - I||^2 == ||G - P||^2 (P orthogonal) — no matmul.

#define TILE 256
#define SCALED_ITERS 3
#define PLAIN_ITERS  1

__device__ __forceinline__ float se3_elem(const float* __restrict__ R,  // 9
                                          const float* __restrict__ Q,  // 7
                                          const float* __restrict__ T)  // 3
{
    float w  = Q[0], x = Q[1], y = Q[2], z = Q[3];

    // closed-form polar of quat matrix
    float v2 = x*x + y*y + z*z;
    float c  = 1.0f - 2.0f*v2;
    float r2 = fmaxf(c*c + 4.0f*(w*w)*v2, 1e-30f);
    float rr = __builtin_amdgcn_rsqf(r2);
    float ga = c * rr;
    float gt_ = (1.0f - ga) * __builtin_amdgcn_rcpf(fmaxf(v2, 1e-37f));
    float gb = 2.0f * w * rr;

    float tx = gt_*x, ty = gt_*y, tz = gt_*z;
    float bx = gb*x,  by = gb*y,  bz = gb*z;

    float G0 = ga + tx*x,  G1 = tx*y - bz,   G2 = tx*z + by;
    float G3 = tx*y + bz,  G4 = ga + ty*y,   G5 = ty*z - bx;
    float G6 = tx*z - by,  G7 = ty*z + bx,   G8 = ga + tz*z;

    // polar of pred_R: 3 scaled + 1 plain Newton iterations
    float X0 = R[0], X1 = R[1], X2 = R[2];
    float X3 = R[3], X4 = R[4], X5 = R[5];
    float X6 = R[6], X7 = R[7], X8 = R[8];

    float s = 1.0f;
#pragma unroll
    for (int it = 0; it < SCALED_ITERS + PLAIN_ITERS; ++it) {
        float C0 = X4*X8 - X5*X7;
        float C1 = X5*X6 - X3*X8;
        float C2 = X3*X7 - X4*X6;
        float C3 = X2*X7 - X1*X8;
        float C4 = X0*X8 - X2*X6;
        float C5 = X1*X6 - X0*X7;
        float C6 = X1*X5 - X2*X4;
        float C7 = X2*X3 - X0*X5;
        float C8 = X0*X4 - X1*X3;
        float det = X0*C0 + X1*C1 + X2*C2;
        if (it == 0) s = (det < 0.0f) ? -1.0f : 1.0f;
        float ka, kb;
        if (it < SCALED_ITERS) {
            float ad = fminf(fmaxf(fabsf(det), 1e-30f), 1e30f);
            float g  = __builtin_amdgcn_exp2f(0.33333333f * __builtin_amdgcn_logf(ad));
            ka = 0.5f * __builtin_amdgcn_rcpf(g);
            kb = 0.5f * g * __builtin_amdgcn_rcpf(det);
        } else {
            ka = 0.5f;
            kb = 0.5f * __builtin_amdgcn_rcpf(det);
        }
        if (it == SCALED_ITERS + PLAIN_ITERS - 1) { ka *= s; kb *= s; }
        X0 = ka*X0 + kb*C0;  X1 = ka*X1 + kb*C1;  X2 = ka*X2 + kb*C2;
        X3 = ka*X3 + kb*C3;  X4 = ka*X4 + kb*C4;  X5 = ka*X5 + kb*C5;
        X6 = ka*X6 + kb*C6;  X7 = ka*X7 + kb*C7;  X8 = ka*X8 + kb*C8;
    }

    float d0 = G0-X0, d1 = G1-X1, d2 = G2-X2;
    float d3 = G3-X3, d4 = G4-X4, d5 = G5-X5;
    float d6 = G6-X6, d7 = G7-X7, d8 = G8-X8;
    float rot = d0*d0 + d1*d1 + d2*d2
              + d3*d3 + d4*d4 + d5*d5
              + d6*d6 + d7*d7 + d8*d8;

    float e0 = T[0] - Q[4];
    float e1 = T[1] - Q[5];
    float e2 = T[2] - Q[6];
    float tl = e0*e0 + e1*e1 + e2*e2;

    return rot * (1.0f/9.0f) + tl * (1.0f/3.0f);   // 1/B applied by caller
}

__global__ __launch_bounds__(256, 8) void se3_loss_kernel(
    const float* __restrict__ pred_R,
    const float* __restrict__ pred_t,
    const float* __restrict__ gt,
    float* __restrict__ out, int B, float invB)
{
    // 19456 B of tile storage + 16 B reduction scratch -> 8 blocks/CU.
    __shared__ __align__(16) float ldsR[TILE * 9];
    __shared__ __align__(16) float ldsQ[TILE * 7];
    __shared__ __align__(16) float ldsT[TILE * 3];
    __shared__ float wsums[4];

    const int tid  = threadIdx.x;
    const int base = blockIdx.x * TILE;
    int count = B - base;
    if (count > TILE) count = TILE;

    if (count == TILE) {
        // Fully coalesced staging: per wave-load, 64 lanes x 16B contiguous.
        // R: 576 float4 / 256 thr, Q: 448, T: 192. Tail predicates are
        // wave-uniform (tid<64 -> wave 0 only; tid<192 -> waves 0-2).
        const float4* sR = reinterpret_cast<const float4*>(pred_R) + (size_t)blockIdx.x * (TILE * 9 / 4);
        const float4* sQ = reinterpret_cast<const float4*>(gt)     + (size_t)blockIdx.x * (TILE * 7 / 4);
        const float4* sT = reinterpret_cast<const float4*>(pred_t) + (size_t)blockIdx.x * (TILE * 3 / 4);
        float4* dR = reinterpret_cast<float4*>(ldsR);
        float4* dQ = reinterpret_cast<float4*>(ldsQ);
        float4* dT = reinterpret_cast<float4*>(ldsT);

        // Issue all global loads first (max MLP), then the LDS writes.
        float4 r0 = sR[tid];
        float4 r1 = sR[tid + 256];
        float4 r2; if (tid < 64)  r2 = sR[tid + 512];
        float4 q0 = sQ[tid];
        float4 q1; if (tid < 192) q1 = sQ[tid + 256];
        float4 t0; if (tid < 192) t0 = sT[tid];

        dR[tid]       = r0;
        dR[tid + 256] = r1;
        if (tid < 64)  dR[tid + 512] = r2;
        dQ[tid]       = q0;
        if (tid < 192) dQ[tid + 256] = q1;
        if (tid < 192) dT[tid]       = t0;
    } else {
        // Partial last tile (not taken at B = 1048576): scalar staging.
        for (int i = tid; i < count * 9; i += 256) ldsR[i] = pred_R[(size_t)base * 9 + i];
        for (int i = tid; i < count * 7; i += 256) ldsQ[i] = gt[(size_t)base * 7 + i];
        for (int i = tid; i < count * 3; i += 256) ldsT[i] = pred_t[(size_t)base * 3 + i];
    }
    __syncthreads();

    // One element per thread out of LDS. Read strides 9/7/3 floats are odd ->
    // lanes 0-31 hit 32 distinct banks, lanes 32-63 alias 2-way (free).
    float acc = 0.0f;
    if (tid < count)
        acc = se3_elem(&ldsR[9 * tid], &ldsQ[7 * tid], &ldsT[3 * tid]) * invB;

    // reduction: wave shuffle -> LDS -> 1 atomic/block
#pragma unroll
    for (int off = 32; off > 0; off >>= 1)
        acc += __shfl_down(acc, off, 64);

    int lane = tid & 63;
    int wid  = tid >> 6;
    if (lane == 0) wsums[wid] = acc;
    __syncthreads();
    if (tid == 0) {
        float tot = wsums[0] + wsums[1] + wsums[2] + wsums[3];
        atomicAdd(out, tot);
    }
}

extern "C" void kernel_launch(void* const* d_in, const int* in_sizes, int n_in,
                              void* d_out, int out_size, void* d_ws, size_t ws_size,
                              hipStream_t stream) {
    const float* pred_R = (const float*)d_in[0];
    const float* pred_t = (const float*)d_in[1];
    const float* gt     = (const float*)d_in[2];
    float* out = (float*)d_out;
    int B = in_sizes[0] / 9;

    hipMemsetAsync(out, 0, sizeof(float), stream);

    const int block = 256;
    const int grid  = (B + TILE - 1) / TILE;   // 4096 blocks, 1 tile each
    se3_loss_kernel<<<grid, block, 0, stream>>>(pred_R, pred_t, gt, out, B,
                                                1.0f / (float)B);
}

// Round 2
// 143.806 us; speedup vs baseline: 1.0112x; 1.0112x over previous
//
#include <hip/hip_runtime.h>

// SE3 loss, round 7: round-6 structure with the register-spill fixed.
// Round-6 post-mortem: __launch_bounds__(256,8) capped VGPRs at 32, but
// se3_elem holds ~35 live floats across the Newton loop (9 X + 9 C + 9 G +
// temps) -> scratch spill inside a 4-deep dependent loop. Signature: VGPR=32,
// VALUBusy 14% (stalled, not issuing), HBM 8%, dur 50->60us regression.
// Single-variable fix: bound (256,6) -> VGPR cap ~80 (need ~60-70, no spill),
// 6 waves/SIMD. Staging + LDS redistribution unchanged (coalesced, 0 bank
// conflicts, FETCH showed zero over-fetch).
//
// Math per element unchanged (verified, absmax 0.0):
//  - G (gt rotation): closed-form SVD polar factor of the unnormalized-quat
//    matrix: polar(G) = (c/r)I + ((1-c/r)/v^2) vv^T + (2w/r)[v]x.
//  - P (pred_R): 3 determinant-scaled Newton iterations + 1 unscaled polish;
//    sign(det0) flip folded into final iteration's coefficients.
//  - rot loss: ||P^T G - I||^2 == ||G - P||^2 (P orthogonal) — no matmul.

#define TILE 256
#define SCALED_ITERS 3
#define PLAIN_ITERS  1

__device__ __forceinline__ float se3_elem(const float* __restrict__ R,  // 9
                                          const float* __restrict__ Q,  // 7
                                          const float* __restrict__ T)  // 3
{
    float w  = Q[0], x = Q[1], y = Q[2], z = Q[3];

    // closed-form polar of quat matrix
    float v2 = x*x + y*y + z*z;
    float c  = 1.0f - 2.0f*v2;
    float r2 = fmaxf(c*c + 4.0f*(w*w)*v2, 1e-30f);
    float rr = __builtin_amdgcn_rsqf(r2);
    float ga = c * rr;
    float gt_ = (1.0f - ga) * __builtin_amdgcn_rcpf(fmaxf(v2, 1e-37f));
    float gb = 2.0f * w * rr;

    float tx = gt_*x, ty = gt_*y, tz = gt_*z;
    float bx = gb*x,  by = gb*y,  bz = gb*z;

    float G0 = ga + tx*x,  G1 = tx*y - bz,   G2 = tx*z + by;
    float G3 = tx*y + bz,  G4 = ga + ty*y,   G5 = ty*z - bx;
    float G6 = tx*z - by,  G7 = ty*z + bx,   G8 = ga + tz*z;

    // polar of pred_R: 3 scaled + 1 plain Newton iterations
    float X0 = R[0], X1 = R[1], X2 = R[2];
    float X3 = R[3], X4 = R[4], X5 = R[5];
    float X6 = R[6], X7 = R[7], X8 = R[8];

    float s = 1.0f;
#pragma unroll
    for (int it = 0; it < SCALED_ITERS + PLAIN_ITERS; ++it) {
        float C0 = X4*X8 - X5*X7;
        float C1 = X5*X6 - X3*X8;
        float C2 = X3*X7 - X4*X6;
        float C3 = X2*X7 - X1*X8;
        float C4 = X0*X8 - X2*X6;
        float C5 = X1*X6 - X0*X7;
        float C6 = X1*X5 - X2*X4;
        float C7 = X2*X3 - X0*X5;
        float C8 = X0*X4 - X1*X3;
        float det = X0*C0 + X1*C1 + X2*C2;
        if (it == 0) s = (det < 0.0f) ? -1.0f : 1.0f;
        float ka, kb;
        if (it < SCALED_ITERS) {
            float ad = fminf(fmaxf(fabsf(det), 1e-30f), 1e30f);
            float g  = __builtin_amdgcn_exp2f(0.33333333f * __builtin_amdgcn_logf(ad));
            ka = 0.5f * __builtin_amdgcn_rcpf(g);
            kb = 0.5f * g * __builtin_amdgcn_rcpf(det);
        } else {
            ka = 0.5f;
            kb = 0.5f * __builtin_amdgcn_rcpf(det);
        }
        if (it == SCALED_ITERS + PLAIN_ITERS - 1) { ka *= s; kb *= s; }
        X0 = ka*X0 + kb*C0;  X1 = ka*X1 + kb*C1;  X2 = ka*X2 + kb*C2;
        X3 = ka*X3 + kb*C3;  X4 = ka*X4 + kb*C4;  X5 = ka*X5 + kb*C5;
        X6 = ka*X6 + kb*C6;  X7 = ka*X7 + kb*C7;  X8 = ka*X8 + kb*C8;
    }

    float d0 = G0-X0, d1 = G1-X1, d2 = G2-X2;
    float d3 = G3-X3, d4 = G4-X4, d5 = G5-X5;
    float d6 = G6-X6, d7 = G7-X7, d8 = G8-X8;
    float rot = d0*d0 + d1*d1 + d2*d2
              + d3*d3 + d4*d4 + d5*d5
              + d6*d6 + d7*d7 + d8*d8;

    float e0 = T[0] - Q[4];
    float e1 = T[1] - Q[5];
    float e2 = T[2] - Q[6];
    float tl = e0*e0 + e1*e1 + e2*e2;

    return rot * (1.0f/9.0f) + tl * (1.0f/3.0f);   // 1/B applied by caller
}

__global__ __launch_bounds__(256, 6) void se3_loss_kernel(
    const float* __restrict__ pred_R,
    const float* __restrict__ pred_t,
    const float* __restrict__ gt,
    float* __restrict__ out, int B, float invB)
{
    __shared__ __align__(16) float ldsR[TILE * 9];
    __shared__ __align__(16) float ldsQ[TILE * 7];
    __shared__ __align__(16) float ldsT[TILE * 3];
    __shared__ float wsums[4];

    const int tid  = threadIdx.x;
    const int base = blockIdx.x * TILE;
    int count = B - base;
    if (count > TILE) count = TILE;

    if (count == TILE) {
        // Fully coalesced staging: per wave-load, 64 lanes x 16B contiguous.
        // Tail predicates are wave-uniform (tid<64 -> wave 0; tid<192 -> w0-2).
        const float4* sR = reinterpret_cast<const float4*>(pred_R) + (size_t)blockIdx.x * (TILE * 9 / 4);
        const float4* sQ = reinterpret_cast<const float4*>(gt)     + (size_t)blockIdx.x * (TILE * 7 / 4);
        const float4* sT = reinterpret_cast<const float4*>(pred_t) + (size_t)blockIdx.x * (TILE * 3 / 4);
        float4* dR = reinterpret_cast<float4*>(ldsR);
        float4* dQ = reinterpret_cast<float4*>(ldsQ);
        float4* dT = reinterpret_cast<float4*>(ldsT);

        // Issue all global loads first (max MLP), then the LDS writes.
        float4 r0 = sR[tid];
        float4 r1 = sR[tid + 256];
        float4 r2; if (tid < 64)  r2 = sR[tid + 512];
        float4 q0 = sQ[tid];
        float4 q1; if (tid < 192) q1 = sQ[tid + 256];
        float4 t0; if (tid < 192) t0 = sT[tid];

        dR[tid]       = r0;
        dR[tid + 256] = r1;
        if (tid < 64)  dR[tid + 512] = r2;
        dQ[tid]       = q0;
        if (tid < 192) dQ[tid + 256] = q1;
        if (tid < 192) dT[tid]       = t0;
    } else {
        // Partial last tile (not taken at B = 1048576): scalar staging.
        for (int i = tid; i < count * 9; i += 256) ldsR[i] = pred_R[(size_t)base * 9 + i];
        for (int i = tid; i < count * 7; i += 256) ldsQ[i] = gt[(size_t)base * 7 + i];
        for (int i = tid; i < count * 3; i += 256) ldsT[i] = pred_t[(size_t)base * 3 + i];
    }
    __syncthreads();

    // One element per thread out of LDS. Read strides 9/7/3 floats are odd ->
    // lanes 0-31 hit 32 distinct banks, lanes 32-63 alias 2-way (free).
    float acc = 0.0f;
    if (tid < count)
        acc = se3_elem(&ldsR[9 * tid], &ldsQ[7 * tid], &ldsT[3 * tid]) * invB;

    // reduction: wave shuffle -> LDS -> 1 atomic/block
#pragma unroll
    for (int off = 32; off > 0; off >>= 1)
        acc += __shfl_down(acc, off, 64);

    int lane = tid & 63;
    int wid  = tid >> 6;
    if (lane == 0) wsums[wid] = acc;
    __syncthreads();
    if (tid == 0) {
        float tot = wsums[0] + wsums[1] + wsums[2] + wsums[3];
        atomicAdd(out, tot);
    }
}

extern "C" void kernel_launch(void* const* d_in, const int* in_sizes, int n_in,
                              void* d_out, int out_size, void* d_ws, size_t ws_size,
                              hipStream_t stream) {
    const float* pred_R = (const float*)d_in[0];
    const float* pred_t = (const float*)d_in[1];
    const float* gt     = (const float*)d_in[2];
    float* out = (float*)d_out;
    int B = in_sizes[0] / 9;

    hipMemsetAsync(out, 0, sizeof(float), stream);

    const int block = 256;
    const int grid  = (B + TILE - 1) / TILE;   // 4096 blocks, 1 tile each
    se3_loss_kernel<<<grid, block, 0, stream>>>(pred_R, pred_t, gt, out, B,
                                                1.0f / (float)B);
}

// Round 3
// 106.646 us; speedup vs baseline: 1.3635x; 1.3484x over previous
//
#include <hip/hip_runtime.h>

// SE3 loss, round 8: kill the contended-atomic serializer.
// Round 6/7 post-mortem: dur was 60.5us INDEPENDENT of memory traffic
// (dispatches with 131KB hbm_bytes == dispatches with 40MB, both 60us;
// VALUBusy 14%, occ 43%). VGPR=32 is natural allocation, no spill (no
// scratch traffic). The fixed cost tracks the same-address atomicAdd count:
// 1024 atomics -> 50us total (hidden under memory), 4096 atomics -> 60us
// exposed (~15ns/contended cross-XCD atomic). Fix: two-stage reduction —
// K1 writes per-block partials to workspace with a plain store (no
// contention), K2 (1 block) reduces partials -> out. Staging/compute
// structure from round 6 unchanged (coalesced, 0 bank conflicts).
//
// Math per element unchanged (verified, absmax 0.0):
//  - G (gt rotation): closed-form SVD polar factor of the unnormalized-quat
//    matrix: polar(G) = (c/r)I + ((1-c/r)/v^2) vv^T + (2w/r)[v]x.
//  - P (pred_R): 3 determinant-scaled Newton iterations + 1 unscaled polish;
//    sign(det0) flip folded into final iteration's coefficients.
//  - rot loss: ||P^T G - I||^2 == ||G - P||^2 (P orthogonal) — no matmul.

#define TILE 256
#define SCALED_ITERS 3
#define PLAIN_ITERS  1

__device__ __forceinline__ float se3_elem(const float* __restrict__ R,  // 9
                                          const float* __restrict__ Q,  // 7
                                          const float* __restrict__ T)  // 3
{
    float w  = Q[0], x = Q[1], y = Q[2], z = Q[3];

    // closed-form polar of quat matrix
    float v2 = x*x + y*y + z*z;
    float c  = 1.0f - 2.0f*v2;
    float r2 = fmaxf(c*c + 4.0f*(w*w)*v2, 1e-30f);
    float rr = __builtin_amdgcn_rsqf(r2);
    float ga = c * rr;
    float gt_ = (1.0f - ga) * __builtin_amdgcn_rcpf(fmaxf(v2, 1e-37f));
    float gb = 2.0f * w * rr;

    float tx = gt_*x, ty = gt_*y, tz = gt_*z;
    float bx = gb*x,  by = gb*y,  bz = gb*z;

    float G0 = ga + tx*x,  G1 = tx*y - bz,   G2 = tx*z + by;
    float G3 = tx*y + bz,  G4 = ga + ty*y,   G5 = ty*z - bx;
    float G6 = tx*z - by,  G7 = ty*z + bx,   G8 = ga + tz*z;

    // polar of pred_R: 3 scaled + 1 plain Newton iterations
    float X0 = R[0], X1 = R[1], X2 = R[2];
    float X3 = R[3], X4 = R[4], X5 = R[5];
    float X6 = R[6], X7 = R[7], X8 = R[8];

    float s = 1.0f;
#pragma unroll
    for (int it = 0; it < SCALED_ITERS + PLAIN_ITERS; ++it) {
        float C0 = X4*X8 - X5*X7;
        float C1 = X5*X6 - X3*X8;
        float C2 = X3*X7 - X4*X6;
        float C3 = X2*X7 - X1*X8;
        float C4 = X0*X8 - X2*X6;
        float C5 = X1*X6 - X0*X7;
        float C6 = X1*X5 - X2*X4;
        float C7 = X2*X3 - X0*X5;
        float C8 = X0*X4 - X1*X3;
        float det = X0*C0 + X1*C1 + X2*C2;
        if (it == 0) s = (det < 0.0f) ? -1.0f : 1.0f;
        float ka, kb;
        if (it < SCALED_ITERS) {
            float ad = fminf(fmaxf(fabsf(det), 1e-30f), 1e30f);
            float g  = __builtin_amdgcn_exp2f(0.33333333f * __builtin_amdgcn_logf(ad));
            ka = 0.5f * __builtin_amdgcn_rcpf(g);
            kb = 0.5f * g * __builtin_amdgcn_rcpf(det);
        } else {
            ka = 0.5f;
            kb = 0.5f * __builtin_amdgcn_rcpf(det);
        }
        if (it == SCALED_ITERS + PLAIN_ITERS - 1) { ka *= s; kb *= s; }
        X0 = ka*X0 + kb*C0;  X1 = ka*X1 + kb*C1;  X2 = ka*X2 + kb*C2;
        X3 = ka*X3 + kb*C3;  X4 = ka*X4 + kb*C4;  X5 = ka*X5 + kb*C5;
        X6 = ka*X6 + kb*C6;  X7 = ka*X7 + kb*C7;  X8 = ka*X8 + kb*C8;
    }

    float d0 = G0-X0, d1 = G1-X1, d2 = G2-X2;
    float d3 = G3-X3, d4 = G4-X4, d5 = G5-X5;
    float d6 = G6-X6, d7 = G7-X7, d8 = G8-X8;
    float rot = d0*d0 + d1*d1 + d2*d2
              + d3*d3 + d4*d4 + d5*d5
              + d6*d6 + d7*d7 + d8*d8;

    float e0 = T[0] - Q[4];
    float e1 = T[1] - Q[5];
    float e2 = T[2] - Q[6];
    float tl = e0*e0 + e1*e1 + e2*e2;

    return rot * (1.0f/9.0f) + tl * (1.0f/3.0f);   // 1/B applied by caller
}

// Shared body: computes the per-block partial sum (scaled by invB).
__device__ __forceinline__ float se3_block_partial(
    const float* __restrict__ pred_R,
    const float* __restrict__ pred_t,
    const float* __restrict__ gt,
    int B, float invB,
    float* ldsR, float* ldsQ, float* ldsT, float* wsums)
{
    const int tid  = threadIdx.x;
    const int base = blockIdx.x * TILE;
    int count = B - base;
    if (count > TILE) count = TILE;

    if (count == TILE) {
        // Fully coalesced staging: per wave-load, 64 lanes x 16B contiguous.
        // Tail predicates are wave-uniform (tid<64 -> wave 0; tid<192 -> w0-2).
        const float4* sR = reinterpret_cast<const float4*>(pred_R) + (size_t)blockIdx.x * (TILE * 9 / 4);
        const float4* sQ = reinterpret_cast<const float4*>(gt)     + (size_t)blockIdx.x * (TILE * 7 / 4);
        const float4* sT = reinterpret_cast<const float4*>(pred_t) + (size_t)blockIdx.x * (TILE * 3 / 4);
        float4* dR = reinterpret_cast<float4*>(ldsR);
        float4* dQ = reinterpret_cast<float4*>(ldsQ);
        float4* dT = reinterpret_cast<float4*>(ldsT);

        // Issue all global loads first (max MLP), then the LDS writes.
        float4 r0 = sR[tid];
        float4 r1 = sR[tid + 256];
        float4 r2; if (tid < 64)  r2 = sR[tid + 512];
        float4 q0 = sQ[tid];
        float4 q1; if (tid < 192) q1 = sQ[tid + 256];
        float4 t0; if (tid < 192) t0 = sT[tid];

        dR[tid]       = r0;
        dR[tid + 256] = r1;
        if (tid < 64)  dR[tid + 512] = r2;
        dQ[tid]       = q0;
        if (tid < 192) dQ[tid + 256] = q1;
        if (tid < 192) dT[tid]       = t0;
    } else {
        // Partial last tile (not taken at B = 1048576): scalar staging.
        for (int i = tid; i < count * 9; i += 256) ldsR[i] = pred_R[(size_t)base * 9 + i];
        for (int i = tid; i < count * 7; i += 256) ldsQ[i] = gt[(size_t)base * 7 + i];
        for (int i = tid; i < count * 3; i += 256) ldsT[i] = pred_t[(size_t)base * 3 + i];
    }
    __syncthreads();

    // One element per thread out of LDS. Read strides 9/7/3 floats are odd ->
    // lanes 0-31 hit 32 distinct banks, lanes 32-63 alias 2-way (free).
    float acc = 0.0f;
    if (tid < count)
        acc = se3_elem(&ldsR[9 * tid], &ldsQ[7 * tid], &ldsT[3 * tid]) * invB;

    // reduction: wave shuffle -> LDS -> block total
#pragma unroll
    for (int off = 32; off > 0; off >>= 1)
        acc += __shfl_down(acc, off, 64);

    int lane = tid & 63;
    int wid  = tid >> 6;
    if (lane == 0) wsums[wid] = acc;
    __syncthreads();
    return wsums[0] + wsums[1] + wsums[2] + wsums[3];
}

__global__ __launch_bounds__(256) void se3_partial_kernel(
    const float* __restrict__ pred_R,
    const float* __restrict__ pred_t,
    const float* __restrict__ gt,
    float* __restrict__ partials, int B, float invB)
{
    __shared__ __align__(16) float ldsR[TILE * 9];
    __shared__ __align__(16) float ldsQ[TILE * 7];
    __shared__ __align__(16) float ldsT[TILE * 3];
    __shared__ float wsums[4];

    float tot = se3_block_partial(pred_R, pred_t, gt, B, invB,
                                  ldsR, ldsQ, ldsT, wsums);
    if (threadIdx.x == 0)
        partials[blockIdx.x] = tot;      // plain store: zero contention
}

// Fallback (workspace too small): old contended-atomic ending.
__global__ __launch_bounds__(256) void se3_atomic_kernel(
    const float* __restrict__ pred_R,
    const float* __restrict__ pred_t,
    const float* __restrict__ gt,
    float* __restrict__ out, int B, float invB)
{
    __shared__ __align__(16) float ldsR[TILE * 9];
    __shared__ __align__(16) float ldsQ[TILE * 7];
    __shared__ __align__(16) float ldsT[TILE * 3];
    __shared__ float wsums[4];

    float tot = se3_block_partial(pred_R, pred_t, gt, B, invB,
                                  ldsR, ldsQ, ldsT, wsums);
    if (threadIdx.x == 0)
        atomicAdd(out, tot);
}

__global__ __launch_bounds__(256) void se3_reduce_kernel(
    const float* __restrict__ partials, float* __restrict__ out, int n)
{
    float acc = 0.0f;
    for (int i = threadIdx.x; i < n; i += 256)
        acc += partials[i];

#pragma unroll
    for (int off = 32; off > 0; off >>= 1)
        acc += __shfl_down(acc, off, 64);

    __shared__ float wsums[4];
    int lane = threadIdx.x & 63;
    int wid  = threadIdx.x >> 6;
    if (lane == 0) wsums[wid] = acc;
    __syncthreads();
    if (threadIdx.x == 0)
        out[0] = wsums[0] + wsums[1] + wsums[2] + wsums[3];
}

extern "C" void kernel_launch(void* const* d_in, const int* in_sizes, int n_in,
                              void* d_out, int out_size, void* d_ws, size_t ws_size,
                              hipStream_t stream) {
    const float* pred_R = (const float*)d_in[0];
    const float* pred_t = (const float*)d_in[1];
    const float* gt     = (const float*)d_in[2];
    float* out = (float*)d_out;
    int B = in_sizes[0] / 9;

    const int block = 256;
    const int grid  = (B + TILE - 1) / TILE;   // 4096 blocks, 1 tile each

    if (d_ws != nullptr && ws_size >= (size_t)grid * sizeof(float)) {
        float* partials = (float*)d_ws;
        se3_partial_kernel<<<grid, block, 0, stream>>>(pred_R, pred_t, gt,
                                                       partials, B,
                                                       1.0f / (float)B);
        se3_reduce_kernel<<<1, block, 0, stream>>>(partials, out, grid);
    } else {
        hipMemsetAsync(out, 0, sizeof(float), stream);
        se3_atomic_kernel<<<grid, block, 0, stream>>>(pred_R, pred_t, gt,
                                                      out, B, 1.0f / (float)B);
    }
}

// Round 4
// 106.460 us; speedup vs baseline: 1.3659x; 1.0017x over previous
//
#include <hip/hip_runtime.h>

// SE3 loss, round 9: break the load/compute phase lockstep.
// Round-8 post-mortem: two-stage reduction worked (-37us; 4096 contended
// atomics were ~15ns each serialized). The 41us fillBufferAligned rows are
// the harness re-poisoning the 268MB workspace OUTSIDE the timed region
// (41+69 > 106.6 total), so d_ws is free. Residual K1 ~25-30us vs ~13us
// floor: every block did one-shot {bulk load -> barrier -> compute -> exit},
// so resident blocks burst memory (VALU idle) then compute (memory idle).
// Fix: 1024 blocks x 4 tiles, double-buffered LDS (39KB -> 4 blocks/CU),
// per tile: issue global loads for t+1 into regs WHILE computing t from LDS,
// then write regs->LDS after the barrier. Memory and VALU stay co-busy.
//
// Math per element unchanged (verified, absmax 0.0):
//  - G (gt rotation): closed-form SVD polar factor of the unnormalized-quat
//    matrix: polar(G) = (c/r)I + ((1-c/r)/v^2) vv^T + (2w/r)[v]x.
//  - P (pred_R): 3 determinant-scaled Newton iterations + 1 unscaled polish;
//    sign(det0) flip folded into final iteration's coefficients.
//  - rot loss: ||P^T G - I||^2 == ||G - P||^2 (P orthogonal) — no matmul.

#define TILE 256
#define TPB_TILES 4
#define SCALED_ITERS 3
#define PLAIN_ITERS  1

__device__ __forceinline__ float se3_elem(const float* __restrict__ R,  // 9
                                          const float* __restrict__ Q,  // 7
                                          const float* __restrict__ T)  // 3
{
    float w  = Q[0], x = Q[1], y = Q[2], z = Q[3];

    // closed-form polar of quat matrix
    float v2 = x*x + y*y + z*z;
    float c  = 1.0f - 2.0f*v2;
    float r2 = fmaxf(c*c + 4.0f*(w*w)*v2, 1e-30f);
    float rr = __builtin_amdgcn_rsqf(r2);
    float ga = c * rr;
    float gt_ = (1.0f - ga) * __builtin_amdgcn_rcpf(fmaxf(v2, 1e-37f));
    float gb = 2.0f * w * rr;

    float tx = gt_*x, ty = gt_*y, tz = gt_*z;
    float bx = gb*x,  by = gb*y,  bz = gb*z;

    float G0 = ga + tx*x,  G1 = tx*y - bz,   G2 = tx*z + by;
    float G3 = tx*y + bz,  G4 = ga + ty*y,   G5 = ty*z - bx;
    float G6 = tx*z - by,  G7 = ty*z + bx,   G8 = ga + tz*z;

    // polar of pred_R: 3 scaled + 1 plain Newton iterations
    float X0 = R[0], X1 = R[1], X2 = R[2];
    float X3 = R[3], X4 = R[4], X5 = R[5];
    float X6 = R[6], X7 = R[7], X8 = R[8];

    float s = 1.0f;
#pragma unroll
    for (int it = 0; it < SCALED_ITERS + PLAIN_ITERS; ++it) {
        float C0 = X4*X8 - X5*X7;
        float C1 = X5*X6 - X3*X8;
        float C2 = X3*X7 - X4*X6;
        float C3 = X2*X7 - X1*X8;
        float C4 = X0*X8 - X2*X6;
        float C5 = X1*X6 - X0*X7;
        float C6 = X1*X5 - X2*X4;
        float C7 = X2*X3 - X0*X5;
        float C8 = X0*X4 - X1*X3;
        float det = X0*C0 + X1*C1 + X2*C2;
        if (it == 0) s = (det < 0.0f) ? -1.0f : 1.0f;
        float ka, kb;
        if (it < SCALED_ITERS) {
            float ad = fminf(fmaxf(fabsf(det), 1e-30f), 1e30f);
            float g  = __builtin_amdgcn_exp2f(0.33333333f * __builtin_amdgcn_logf(ad));
            ka = 0.5f * __builtin_amdgcn_rcpf(g);
            kb = 0.5f * g * __builtin_amdgcn_rcpf(det);
        } else {
            ka = 0.5f;
            kb = 0.5f * __builtin_amdgcn_rcpf(det);
        }
        if (it == SCALED_ITERS + PLAIN_ITERS - 1) { ka *= s; kb *= s; }
        X0 = ka*X0 + kb*C0;  X1 = ka*X1 + kb*C1;  X2 = ka*X2 + kb*C2;
        X3 = ka*X3 + kb*C3;  X4 = ka*X4 + kb*C4;  X5 = ka*X5 + kb*C5;
        X6 = ka*X6 + kb*C6;  X7 = ka*X7 + kb*C7;  X8 = ka*X8 + kb*C8;
    }

    float d0 = G0-X0, d1 = G1-X1, d2 = G2-X2;
    float d3 = G3-X3, d4 = G4-X4, d5 = G5-X5;
    float d6 = G6-X6, d7 = G7-X7, d8 = G8-X8;
    float rot = d0*d0 + d1*d1 + d2*d2
              + d3*d3 + d4*d4 + d5*d5
              + d6*d6 + d7*d7 + d8*d8;

    float e0 = T[0] - Q[4];
    float e1 = T[1] - Q[5];
    float e2 = T[2] - Q[6];
    float tl = e0*e0 + e1*e1 + e2*e2;

    return rot * (1.0f/9.0f) + tl * (1.0f/3.0f);   // 1/B applied by caller
}

__global__ __launch_bounds__(256) void se3_partial_kernel(
    const float* __restrict__ pred_R,
    const float* __restrict__ pred_t,
    const float* __restrict__ gt,
    float* __restrict__ partials, int B, float invB)
{
    // Double-buffered tiles: 2 x 19456 B + 16 B -> 4 blocks/CU.
    __shared__ __align__(16) float ldsR[2][TILE * 9];
    __shared__ __align__(16) float ldsQ[2][TILE * 7];
    __shared__ __align__(16) float ldsT[2][TILE * 3];
    __shared__ float wsums[4];

    const int tid     = threadIdx.x;
    const int ntiles  = (B + TILE - 1) / TILE;
    const int tile0   = blockIdx.x * TPB_TILES;

    float acc = 0.0f;

    // In-flight staging registers (tile t+1 rides here during compute of t).
    float4 r0, r1, r2, q0, q1, t0;

    auto load_tile = [&](int tile) {
        // Fully coalesced: per wave-load, 64 lanes x 16B contiguous.
        // Tail predicates wave-uniform (tid<64 -> wave 0; tid<192 -> w0-2).
        const float4* sR = reinterpret_cast<const float4*>(pred_R) + (size_t)tile * (TILE * 9 / 4);
        const float4* sQ = reinterpret_cast<const float4*>(gt)     + (size_t)tile * (TILE * 7 / 4);
        const float4* sT = reinterpret_cast<const float4*>(pred_t) + (size_t)tile * (TILE * 3 / 4);
        r0 = sR[tid];
        r1 = sR[tid + 256];
        if (tid < 64)  r2 = sR[tid + 512];
        q0 = sQ[tid];
        if (tid < 192) { q1 = sQ[tid + 256]; t0 = sT[tid]; }
    };
    auto store_tile = [&](int buf) {
        float4* dR = reinterpret_cast<float4*>(ldsR[buf]);
        float4* dQ = reinterpret_cast<float4*>(ldsQ[buf]);
        float4* dT = reinterpret_cast<float4*>(ldsT[buf]);
        dR[tid]       = r0;
        dR[tid + 256] = r1;
        if (tid < 64)  dR[tid + 512] = r2;
        dQ[tid]       = q0;
        if (tid < 192) { dQ[tid + 256] = q1; dT[tid] = t0; }
    };

    const bool all_full = (tile0 + TPB_TILES) * TILE <= B;

    if (all_full) {
        // Pipelined fast path (the only path at B = 1048576):
        //   prologue: load(t0) -> LDS buf0 -> sync
        //   lt: issue-loads(t+1) || compute buf(lt&1) -> sync ->
        //       write buf((lt+1)&1) -> sync
        load_tile(tile0);
        store_tile(0);
        __syncthreads();
#pragma unroll
        for (int lt = 0; lt < TPB_TILES; ++lt) {
            if (lt + 1 < TPB_TILES) load_tile(tile0 + lt + 1);
            const int buf = lt & 1;
            // LDS strides 9/7/3 floats (odd) -> <=2-way bank alias (free).
            acc += se3_elem(&ldsR[buf][9 * tid],
                            &ldsQ[buf][7 * tid],
                            &ldsT[buf][3 * tid]);
            __syncthreads();   // everyone done reading buf before its sibling
                               // gets overwritten next iteration
            if (lt + 1 < TPB_TILES) {
                store_tile((lt + 1) & 1);
                __syncthreads();
            }
        }
        acc *= invB;
    } else {
        // Ragged tail path (not taken at B = 1048576): per-tile scalar staging.
        for (int lt = 0; lt < TPB_TILES; ++lt) {
            const int tile = tile0 + lt;
            if (tile >= ntiles) break;
            const int base  = tile * TILE;
            int count = B - base;
            if (count > TILE) count = TILE;
            __syncthreads();
            for (int i = tid; i < count * 9; i += 256) ldsR[0][i] = pred_R[(size_t)base * 9 + i];
            for (int i = tid; i < count * 7; i += 256) ldsQ[0][i] = gt[(size_t)base * 7 + i];
            for (int i = tid; i < count * 3; i += 256) ldsT[0][i] = pred_t[(size_t)base * 3 + i];
            __syncthreads();
            if (tid < count)
                acc += se3_elem(&ldsR[0][9 * tid], &ldsQ[0][7 * tid], &ldsT[0][3 * tid]);
        }
        acc *= invB;
    }

    // reduction: wave shuffle -> LDS -> one plain store per block
#pragma unroll
    for (int off = 32; off > 0; off >>= 1)
        acc += __shfl_down(acc, off, 64);

    int lane = tid & 63;
    int wid  = tid >> 6;
    if (lane == 0) wsums[wid] = acc;
    __syncthreads();
    if (tid == 0)
        partials[blockIdx.x] = wsums[0] + wsums[1] + wsums[2] + wsums[3];
}

__global__ __launch_bounds__(256) void se3_reduce_kernel(
    const float* __restrict__ partials, float* __restrict__ out, int n)
{
    float acc = 0.0f;
    for (int i = threadIdx.x; i < n; i += 256)
        acc += partials[i];

#pragma unroll
    for (int off = 32; off > 0; off >>= 1)
        acc += __shfl_down(acc, off, 64);

    __shared__ float wsums[4];
    int lane = threadIdx.x & 63;
    int wid  = threadIdx.x >> 6;
    if (lane == 0) wsums[wid] = acc;
    __syncthreads();
    if (threadIdx.x == 0)
        out[0] = wsums[0] + wsums[1] + wsums[2] + wsums[3];
}

// Fallback (workspace too small): single kernel, contended atomic (slow but
// correct). Uses the simple one-tile-per-block structure.
__global__ __launch_bounds__(256) void se3_atomic_kernel(
    const float* __restrict__ pred_R,
    const float* __restrict__ pred_t,
    const float* __restrict__ gt,
    float* __restrict__ out, int B, float invB)
{
    __shared__ __align__(16) float ldsR[TILE * 9];
    __shared__ __align__(16) float ldsQ[TILE * 7];
    __shared__ __align__(16) float ldsT[TILE * 3];
    __shared__ float wsums[4];

    const int tid  = threadIdx.x;
    const int base = blockIdx.x * TILE;
    int count = B - base;
    if (count > TILE) count = TILE;

    for (int i = tid; i < count * 9; i += 256) ldsR[i] = pred_R[(size_t)base * 9 + i];
    for (int i = tid; i < count * 7; i += 256) ldsQ[i] = gt[(size_t)base * 7 + i];
    for (int i = tid; i < count * 3; i += 256) ldsT[i] = pred_t[(size_t)base * 3 + i];
    __syncthreads();

    float acc = 0.0f;
    if (tid < count)
        acc = se3_elem(&ldsR[9 * tid], &ldsQ[7 * tid], &ldsT[3 * tid]) * invB;

#pragma unroll
    for (int off = 32; off > 0; off >>= 1)
        acc += __shfl_down(acc, off, 64);

    int lane = tid & 63;
    int wid  = tid >> 6;
    if (lane == 0) wsums[wid] = acc;
    __syncthreads();
    if (tid == 0)
        atomicAdd(out, wsums[0] + wsums[1] + wsums[2] + wsums[3]);
}

extern "C" void kernel_launch(void* const* d_in, const int* in_sizes, int n_in,
                              void* d_out, int out_size, void* d_ws, size_t ws_size,
                              hipStream_t stream) {
    const float* pred_R = (const float*)d_in[0];
    const float* pred_t = (const float*)d_in[1];
    const float* gt     = (const float*)d_in[2];
    float* out = (float*)d_out;
    int B = in_sizes[0] / 9;

    const int block  = 256;
    const int ntiles = (B + TILE - 1) / TILE;
    const int grid   = (ntiles + TPB_TILES - 1) / TPB_TILES;   // 1024 blocks

    if (d_ws != nullptr && ws_size >= (size_t)grid * sizeof(float)) {
        float* partials = (float*)d_ws;
        se3_partial_kernel<<<grid, block, 0, stream>>>(pred_R, pred_t, gt,
                                                       partials, B,
                                                       1.0f / (float)B);
        se3_reduce_kernel<<<1, block, 0, stream>>>(partials, out, grid);
    } else {
        hipMemsetAsync(out, 0, sizeof(float), stream);
        se3_atomic_kernel<<<ntiles, block, 0, stream>>>(pred_R, pred_t, gt,
                                                        out, B, 1.0f / (float)B);
    }
}